// Round 10
// baseline (532.105 us; speedup 1.0000x reference)
//
#include <hip/hip_runtime.h>

#define NB 128
#define NL 256
#define NH 512
#define NMAX 256

typedef __attribute__((ext_vector_type(8))) short s8v;
typedef __attribute__((ext_vector_type(4))) float f4v;

struct Params {
  const int* widx;                 // (B, L) int32
  const float* bias[5];            // each (H,) f32: i, fl, fr, o, c
  const unsigned short* wbf;       // ws: 10 x (H,H) bf16, order [gate][side]
  const unsigned short* embbf;     // ws: (VOCAB, H) bf16 (valid during level 1)
  const unsigned short* hcprev;    // prev level: row (b*NKp + node)*2H, h@0 c@H
  unsigned short* hcout;           // this level: row (b*NK + node)*2H
  float* out;                      // (B, 256, H) f32
  float* fh;                       // (B, H)
  float* fc;                       // (B, H)
};

struct PrepParams {
  const float* u[10];
  const float* emb;
  unsigned short* wdst;
  unsigned short* edst;
};

__device__ __forceinline__ float bf2f(unsigned short u) {
  union { unsigned int i; float f; } v;
  v.i = ((unsigned int)u) << 16;
  return v.f;
}
__device__ __forceinline__ unsigned short f2bf(float f) {
  union { float f; unsigned int i; } v;
  v.f = f;
  unsigned int x = v.i;
  x += 0x7fffu + ((x >> 16) & 1u);   // RNE
  return (unsigned short)(x >> 16);
}
__device__ __forceinline__ s8v pack8(f4v a, f4v b) {
  s8v r;
  r[0] = (short)f2bf(a[0]); r[1] = (short)f2bf(a[1]);
  r[2] = (short)f2bf(a[2]); r[3] = (short)f2bf(a[3]);
  r[4] = (short)f2bf(b[0]); r[5] = (short)f2bf(b[1]);
  r[6] = (short)f2bf(b[2]); r[7] = (short)f2bf(b[3]);
  return r;
}
__device__ __forceinline__ float sigf(float x) {
  return 1.f / (1.f + __expf(-x));
}
__device__ __forceinline__ void glds16(const void* g, void* l) {
  __builtin_amdgcn_global_load_lds(
      (const __attribute__((address_space(1))) unsigned int*)g,
      (__attribute__((address_space(3))) unsigned int*)l, 16, 0, 0);
}
__device__ __forceinline__ void barrier_raw() {
  __builtin_amdgcn_sched_barrier(0);
  __builtin_amdgcn_s_barrier();
  __builtin_amdgcn_sched_barrier(0);
}
#define WAITV(N) do { asm volatile("s_waitcnt vmcnt(" #N ")" ::: "memory"); \
                      __builtin_amdgcn_sched_barrier(0); } while (0)
#define LGKM0 do { asm volatile("s_waitcnt lgkmcnt(0)" ::: "memory"); \
                   __builtin_amdgcn_sched_barrier(0); } while (0)

// One prep pass: 10 (H,H) weights + the full emb table, f32 -> bf16.
__global__ __launch_bounds__(256) void prep_cvt(PrepParams pp) {
  int gid = blockIdx.x * 256 + threadIdx.x;
  const float* s;
  unsigned short* d;
  if (gid < 327680) {
    int mat = gid >> 15, off = (gid & 32767) * 8;
    s = pp.u[mat] + off;
    d = pp.wdst + (size_t)mat * NH * NH + off;
  } else {
    size_t off = (size_t)(gid - 327680) * 8;
    s = pp.emb + off;
    d = pp.edst + off;
  }
  f4v x0 = *(const f4v*)s;
  f4v x1 = *(const f4v*)(s + 4);
  *(s8v*)d = pack8(x0, x1);
}

// Post-order position of internal node (k, j): pos = (j+1)*2^k - 2 - popcount(j).
// Output column = pos + 1 (column 0 duplicates node (1,0)).
//
// Block: BM rows x (5 gates x 64 hd) x K=1024.  BM*2 threads = BM/32 waves.
// Wave (mh, q): 128 rows x (5 gates x 16 hd), acc[8][5]; thread-local epilogue.
// K-loop: 4-phase interleave per BK=32 tile (T3), 3 LDS buffers, prefetch
// depth 2, counted per-wave vmcnt once per tile (T4), raw s_barrier pairs,
// setprio around each 10-MFMA cluster (T5).  vmcnt never drains to 0 until
// the final tiles.  XOR swizzle chunk ^= (row>>1)&3 (verified conflict-free).

template<int LEVEL, int BM>
__global__ __launch_bounds__(BM * 2, 2)
void lstm_level(Params p) {
  constexpr int NK = NL >> LEVEL;
  constexpr int LOGNK = 8 - LEVEL;
  constexpr int NKP = NL >> (LEVEL - 1);
  constexpr int M = NB * NK;
  constexpr int W = BM / 32;                    // waves per block
  constexpr int ASUB = BM * 64;                 // A bytes per tile
  constexpr int BUFSZ = ASUB + 20480;
  __shared__ __align__(16) unsigned char lds[3 * BUFSZ];

  const int tid = threadIdx.x;
  const int wid = tid >> 6;
  const int lane = tid & 63;
  const int lhi = lane >> 4, llo = lane & 15;
  const int mh = (BM == 256) ? (wid & 1) : 0;   // m-half (128 rows)
  const int q  = (BM == 256) ? (wid >> 1) : wid; // 16-hd slice
  const int bm = blockIdx.x, ht = blockIdx.y;

  const unsigned short* abase = (LEVEL == 1) ? p.embbf : p.hcprev;

  // ---------- A staging: 2 glds/wave/tile; group gi = rows gi*16..+15 ----------
  int aOffL[2], aOffR[2];
#pragma unroll
  for (int ii = 0; ii < 2; ++ii) {
    int gi = ii * W + wid;
    int ar = gi * 16 + (lane >> 2);
    int ck = (lane & 3) ^ ((ar >> 1) & 3);
    int am = bm * BM + ar; if (am > M - 1) am = M - 1;
    int b = am >> LOGNK, j = am & (NK - 1);
    if constexpr (LEVEL == 1) {
      aOffL[ii] = p.widx[b * NL + 2 * j] * NH + ck * 8;
      aOffR[ii] = p.widx[b * NL + 2 * j + 1] * NH + ck * 8;
    } else {
      int base = (b * NKP + 2 * j) * (2 * NH);
      aOffL[ii] = base + ck * 8;
      aOffR[ii] = base + 2 * NH + ck * 8;
    }
  }

  // ---------- B staging offsets: 20 groups of 16 rows ----------
  constexpr int BI = (20 + W - 1) / W;
  int bOff[BI];
#pragma unroll
  for (int ii = 0; ii < BI; ++ii) {
    int gi = ii * W + wid;
    if (gi < 20) {
      int r = gi * 16 + (lane >> 2);
      int gg = gi >> 2;
      int ck = (lane & 3) ^ ((r >> 1) & 3);
      bOff[ii] = ((2 * gg) * NH + (ht * 64 + (r & 63))) * NH + ck * 8;
    } else bOff[ii] = 0;
  }

  auto stageA = [&](int tt) {
    unsigned char* base = lds + (tt % 3) * BUFSZ;
    const int kw = (tt & 15) * 32;
    const int* ao = (tt < 16) ? aOffL : aOffR;
#pragma unroll
    for (int ii = 0; ii < 2; ++ii)
      glds16(abase + ao[ii] + kw, base + (ii * W + wid) * 1024);
  };
  // part = 0,1,2 -> B stage chunk (per-wave counts: BM=256: 1/1/(wid<4); BM=128: 2/2/1)
  auto stageB = [&](int tt, int part) {
    unsigned char* base = lds + (tt % 3) * BUFSZ + ASUB;
    const int kw = (tt & 15) * 32;
    const size_t wsel = (size_t)(tt >> 4) * NH * NH;
    if constexpr (BM == 256) {
      int gi = part * W + wid;
      if (part < 2 || wid < 4)
        glds16(p.wbf + wsel + bOff[part] + kw, base + gi * 1024);
    } else {
      if (part < 2) {
#pragma unroll
        for (int s2 = 0; s2 < 2; ++s2) {
          int ii = part * 2 + s2;
          glds16(p.wbf + wsel + bOff[ii] + kw, base + (ii * W + wid) * 1024);
        }
      } else {
        glds16(p.wbf + wsel + bOff[4] + kw, base + (4 * W + wid) * 1024);
      }
    }
  };

  // ---------- fragment LDS byte offsets (swizzled reads, tile-relative) ----------
  int aoff[8], boff[5];
#pragma unroll
  for (int fm = 0; fm < 8; ++fm) {
    int r = mh * 128 + fm * 16 + llo;
    aoff[fm] = r * 64 + ((lhi ^ ((r >> 1) & 3)) << 4);
  }
#pragma unroll
  for (int g = 0; g < 5; ++g) {
    int r = g * 64 + q * 16 + llo;
    boff[g] = r * 64 + ((lhi ^ ((r >> 1) & 3)) << 4);
  }

  f4v acc[8][5];
#pragma unroll
  for (int fm = 0; fm < 8; ++fm)
#pragma unroll
    for (int g = 0; g < 5; ++g)
      acc[fm][g] = (f4v){0.f, 0.f, 0.f, 0.f};

#define WAIT_FULL do { if constexpr (BM == 128) { WAITV(7); }            \
    else { if (wid < 4) { WAITV(5); } else { WAITV(4); } } } while (0)

#define RUN_PHASE(F, STAGE_STMT, WAIT_STMT) do {                         \
    s8v xa = *(const s8v*)(Ab + aoff[2*(F)]);                            \
    s8v xb = *(const s8v*)(Ab + aoff[2*(F)+1]);                          \
    STAGE_STMT;                                                          \
    WAIT_STMT;                                                           \
    barrier_raw();                                                       \
    LGKM0;                                                               \
    __builtin_amdgcn_s_setprio(1);                                       \
    _Pragma("unroll")                                                    \
    for (int g = 0; g < 5; ++g) {                                        \
      acc[2*(F)][g]   = __builtin_amdgcn_mfma_f32_16x16x32_bf16(         \
          xa, bv[g], acc[2*(F)][g], 0, 0, 0);                            \
      acc[2*(F)+1][g] = __builtin_amdgcn_mfma_f32_16x16x32_bf16(         \
          xb, bv[g], acc[2*(F)+1][g], 0, 0, 0);                          \
    }                                                                    \
    __builtin_amdgcn_s_setprio(0);                                       \
    barrier_raw();                                                       \
  } while (0)

  // ---------- prologue: tiles 0 and 1 in flight ----------
  stageA(0); stageB(0, 0); stageB(0, 1); stageB(0, 2);
  stageA(1); stageB(1, 0); stageB(1, 1); stageB(1, 2);
  WAIT_FULL;                                    // tile 0 landed (tile 1 in flight)
  barrier_raw();

  // ---------- main K loop: 32 tiles x 4 phases ----------
  for (int t = 0; t < 32; ++t) {
    const unsigned char* Ab = lds + (t % 3) * BUFSZ;
    const unsigned char* Bb = Ab + ASUB;
    const bool st = t < 30;
    const int ts = t + 2;
    s8v bv[5];
#pragma unroll
    for (int g = 0; g < 5; ++g) bv[g] = *(const s8v*)(Bb + boff[g]);
    RUN_PHASE(0, if (st) stageA(ts),      (void)0);
    RUN_PHASE(1, if (st) stageB(ts, 0),   (void)0);
    RUN_PHASE(2, if (st) stageB(ts, 1),   (void)0);
    RUN_PHASE(3, if (st) stageB(ts, 2),
              do { if (t < 30) { WAIT_FULL; } else if (t == 30) { WAITV(0); } } while (0));
  }

  // ---------- epilogue: fully thread-local gate math ----------
  const int hd = ht * 64 + q * 16 + llo;
  float bb[5];
#pragma unroll
  for (int g = 0; g < 5; ++g) bb[g] = p.bias[g][hd];

#pragma unroll
  for (int fm = 0; fm < 8; ++fm) {
#pragma unroll
    for (int jj = 0; jj < 4; ++jj) {
      int m = bm * BM + mh * 128 + fm * 16 + lhi * 4 + jj;
      if (m < M) {
        int b = m >> LOGNK, j = m & (NK - 1);
        float zi  = acc[fm][0][jj] + bb[0];
        float zfl = acc[fm][1][jj] + bb[1];
        float zfr = acc[fm][2][jj] + bb[2];
        float zo  = acc[fm][3][jj] + bb[3];
        float zc  = acc[fm][4][jj] + bb[4];
        float cl = 0.5f, cr = 0.5f;
        if constexpr (LEVEL > 1) {
          const unsigned short* cb =
              p.hcprev + ((size_t)b * NKP + 2 * j) * (2 * NH) + NH;
          cl = bf2f(cb[hd]);
          cr = bf2f(cb[2 * NH + hd]);
        }
        float cnew = sigf(zi) * tanhf(zc) + sigf(zfl) * cl + sigf(zfr) * cr;
        float hnew = sigf(zo) * tanhf(cnew);
        unsigned short* orow = p.hcout + ((size_t)b * NK + j) * (2 * NH);
        orow[hd] = f2bf(hnew);
        orow[NH + hd] = f2bf(cnew);
        int colout = (((j + 1) << LEVEL) - 2 - __popc(j)) + 1;
        p.out[((size_t)b * NMAX + colout) * NH + hd] = hnew;
        if (LEVEL == 1 && j == 0) p.out[(size_t)b * NMAX * NH + hd] = hnew;
        if constexpr (LEVEL == 8) { p.fh[b * NH + hd] = hnew; p.fc[b * NH + hd] = cnew; }
      }
    }
  }
#undef RUN_PHASE
#undef WAIT_FULL
}

extern "C" void kernel_launch(void* const* d_in, const int* in_sizes, int n_in,
                              void* d_out, int out_size, void* d_ws, size_t ws_size,
                              hipStream_t stream) {
  unsigned short* wbf = (unsigned short*)d_ws;            // 2,621,440 elems (5.24 MB)
  unsigned short* R1  = wbf + (size_t)10 * NH * NH;       // 16,777,216 elems (33.55 MB)
  unsigned short* R2  = R1 + 16777216;                    // 16,777,216 elems (33.55 MB)
  // R1 holds embbf for level 1, then outputs of levels 2,4,6,8.
  // R2 holds outputs of levels 1,3,5,7.  Total ws use: 72.35 MB.

  PrepParams pp;
  for (int i = 0; i < 10; ++i) pp.u[i] = (const float*)d_in[2 + i];
  pp.emb  = (const float*)d_in[1];
  pp.wdst = wbf;
  pp.edst = R1;

  Params p;
  p.widx = (const int*)d_in[0];
  for (int g = 0; g < 5; ++g) p.bias[g] = (const float*)d_in[12 + g];
  p.wbf   = wbf;
  p.embbf = R1;
  p.out   = (float*)d_out;
  p.fh    = p.out + (size_t)NB * NMAX * NH;
  p.fc    = p.fh + NB * NH;

  prep_cvt<<<dim3(9280), dim3(256), 0, stream>>>(pp);

  unsigned short* lvlout[9];
  for (int k = 1; k <= 8; ++k) lvlout[k] = (k & 1) ? R2 : R1;

  p.hcprev = nullptr;     p.hcout = lvlout[1];
  lstm_level<1, 256><<<dim3(64, 8), dim3(512), 0, stream>>>(p);
  p.hcprev = lvlout[1];   p.hcout = lvlout[2];
  lstm_level<2, 128><<<dim3(64, 8), dim3(256), 0, stream>>>(p);
  p.hcprev = lvlout[2];   p.hcout = lvlout[3];
  lstm_level<3, 128><<<dim3(32, 8), dim3(256), 0, stream>>>(p);
  p.hcprev = lvlout[3];   p.hcout = lvlout[4];
  lstm_level<4, 128><<<dim3(16, 8), dim3(256), 0, stream>>>(p);
  p.hcprev = lvlout[4];   p.hcout = lvlout[5];
  lstm_level<5, 128><<<dim3(8, 8),  dim3(256), 0, stream>>>(p);
  p.hcprev = lvlout[5];   p.hcout = lvlout[6];
  lstm_level<6, 128><<<dim3(4, 8),  dim3(256), 0, stream>>>(p);
  p.hcprev = lvlout[6];   p.hcout = lvlout[7];
  lstm_level<7, 128><<<dim3(2, 8),  dim3(256), 0, stream>>>(p);
  p.hcprev = lvlout[7];   p.hcout = lvlout[8];
  lstm_level<8, 128><<<dim3(1, 8),  dim3(256), 0, stream>>>(p);
}

// Round 11
// 309.414 us; speedup vs baseline: 1.7197x; 1.7197x over previous
//
#include <hip/hip_runtime.h>

#define NB 128
#define NL 256
#define NH 512
#define NMAX 256

typedef __attribute__((ext_vector_type(8))) short s8v;
typedef __attribute__((ext_vector_type(4))) float f4v;

struct Params {
  const int* widx;                 // (B, L) int32
  const float* bias[5];            // each (H,) f32: i, fl, fr, o, c
  const unsigned short* wbf;       // ws: 10 x (H,H) bf16, order [gate][side]
  const unsigned short* embbf;     // ws: (VOCAB, H) bf16 (valid during level 1)
  const unsigned short* hcprev;    // prev level: row (b*NKp + node)*2H, h@0 c@H
  unsigned short* hcout;           // this level: row (b*NK + node)*2H
  unsigned short* part;            // split-K z-partials (bf16), levels 4-8
  float* out;                      // (B, 256, H) f32
  float* fh;                       // (B, H)
  float* fc;                       // (B, H)
};

struct PrepParams {
  const float* u[10];
  const float* emb;
  unsigned short* wdst;
  unsigned short* edst;
};

__device__ __forceinline__ float bf2f(unsigned short u) {
  union { unsigned int i; float f; } v;
  v.i = ((unsigned int)u) << 16;
  return v.f;
}
__device__ __forceinline__ unsigned short f2bf(float f) {
  union { float f; unsigned int i; } v;
  v.f = f;
  unsigned int x = v.i;
  x += 0x7fffu + ((x >> 16) & 1u);   // RNE
  return (unsigned short)(x >> 16);
}
__device__ __forceinline__ s8v pack8(f4v a, f4v b) {
  s8v r;
  r[0] = (short)f2bf(a[0]); r[1] = (short)f2bf(a[1]);
  r[2] = (short)f2bf(a[2]); r[3] = (short)f2bf(a[3]);
  r[4] = (short)f2bf(b[0]); r[5] = (short)f2bf(b[1]);
  r[6] = (short)f2bf(b[2]); r[7] = (short)f2bf(b[3]);
  return r;
}
__device__ __forceinline__ float sigf(float x) {
  return 1.f / (1.f + __expf(-x));
}
__device__ __forceinline__ void glds16(const void* g, void* l) {
  __builtin_amdgcn_global_load_lds(
      (const __attribute__((address_space(1))) unsigned int*)g,
      (__attribute__((address_space(3))) unsigned int*)l, 16, 0, 0);
}

// One prep pass: 10 (H,H) weights + the full emb table, f32 -> bf16.
__global__ __launch_bounds__(256) void prep_cvt(PrepParams pp) {
  int gid = blockIdx.x * 256 + threadIdx.x;
  const float* s;
  unsigned short* d;
  if (gid < 327680) {
    int mat = gid >> 15, off = (gid & 32767) * 8;
    s = pp.u[mat] + off;
    d = pp.wdst + (size_t)mat * NH * NH + off;
  } else {
    size_t off = (size_t)(gid - 327680) * 8;
    s = pp.emb + off;
    d = pp.edst + off;
  }
  f4v x0 = *(const f4v*)s;
  f4v x1 = *(const f4v*)(s + 4);
  *(s8v*)d = pack8(x0, x1);
}

// Post-order position of internal node (k, j): pos = (j+1)*2^k - 2 - popcount(j).
// Output column = pos + 1 (column 0 duplicates node (1,0)).
//
// GEMM kernel: BM rows x (5 gates x 64 hd) x K-range.  BM*2 threads.
// Wave (mh, q): 128 rows x (5 gates x 16 hd), acc[8][5]; all 5 gates of one
// output element in ONE thread.  Proven 2-phase double-buffered K-loop
// (syncthreads, 2 blocks/CU).  XOR swizzle chunk ^= (row>>1)&3.
// KS>1: split-K — block z = ks computes K-tiles [ks*32/KS, ...), writes bf16
// z-partials to p.part; a separate deterministic combine kernel sums + gates.

template<int LEVEL, int BM, int KS>
__global__ __launch_bounds__(BM * 2, 2)
void lstm_level(Params p) {
  constexpr int NK = NL >> LEVEL;
  constexpr int LOGNK = 8 - LEVEL;
  constexpr int NKP = NL >> (LEVEL - 1);
  constexpr int M = NB * NK;
  constexpr int W = BM / 32;                    // waves per block
  constexpr int ASUB = BM * 64;                 // A bytes per tile
  constexpr int BUFSZ = ASUB + 20480;
  constexpr int NT = 32 / KS;                   // K-tiles this block
  __shared__ __align__(16) unsigned char lds[2 * BUFSZ];

  const int tid = threadIdx.x;
  const int wid = tid >> 6;
  const int lane = tid & 63;
  const int lhi = lane >> 4, llo = lane & 15;
  const int mh = (BM == 256) ? (wid & 1) : 0;   // m-half (128 rows)
  const int q  = (BM == 256) ? (wid >> 1) : wid; // 16-hd slice
  const int bm = blockIdx.x, ht = blockIdx.y;
  const int ks = (KS > 1) ? blockIdx.z : 0;
  const int t0 = ks * NT;

  const unsigned short* abase = (LEVEL == 1) ? p.embbf : p.hcprev;

  // ---------- A staging: 2 glds/wave/tile; group gi = rows gi*16..+15 ----------
  int aOffL[2], aOffR[2];
#pragma unroll
  for (int ii = 0; ii < 2; ++ii) {
    int gi = ii * W + wid;
    int ar = gi * 16 + (lane >> 2);
    int ck = (lane & 3) ^ ((ar >> 1) & 3);
    int am = bm * BM + ar; if (am > M - 1) am = M - 1;
    int b = am >> LOGNK, j = am & (NK - 1);
    if constexpr (LEVEL == 1) {
      aOffL[ii] = p.widx[b * NL + 2 * j] * NH + ck * 8;
      aOffR[ii] = p.widx[b * NL + 2 * j + 1] * NH + ck * 8;
    } else {
      int base = (b * NKP + 2 * j) * (2 * NH);
      aOffL[ii] = base + ck * 8;
      aOffR[ii] = base + 2 * NH + ck * 8;
    }
  }

  // ---------- B staging: 20 groups of 16 rows; row = gate*64 + hd-in-tile ----------
  constexpr int BI = (20 + W - 1) / W;
  int bOff[BI];
#pragma unroll
  for (int ii = 0; ii < BI; ++ii) {
    int gi = ii * W + wid;
    if (gi < 20) {
      int r = gi * 16 + (lane >> 2);
      int gg = gi >> 2;
      int ck = (lane & 3) ^ ((r >> 1) & 3);
      bOff[ii] = ((2 * gg) * NH + (ht * 64 + (r & 63))) * NH + ck * 8;
    } else bOff[ii] = 0;
  }

  auto do_stage = [&](int buf, int tt) {
    unsigned char* base = lds + buf * BUFSZ;
    const int kw = (tt & 15) * 32;
    const int* ao = (tt < 16) ? aOffL : aOffR;
#pragma unroll
    for (int ii = 0; ii < 2; ++ii)
      glds16(abase + ao[ii] + kw, base + (ii * W + wid) * 1024);
    const size_t wsel = (size_t)(tt >> 4) * NH * NH;
#pragma unroll
    for (int ii = 0; ii < BI; ++ii) {
      int gi = ii * W + wid;
      if (gi < 20)
        glds16(p.wbf + wsel + bOff[ii] + kw, base + ASUB + gi * 1024);
    }
  };

  // ---------- fragment LDS byte offsets (swizzled reads, tile-relative) ----------
  int aoff[8], boff[5];
#pragma unroll
  for (int fm = 0; fm < 8; ++fm) {
    int r = mh * 128 + fm * 16 + llo;
    aoff[fm] = r * 64 + ((lhi ^ ((r >> 1) & 3)) << 4);
  }
#pragma unroll
  for (int g = 0; g < 5; ++g) {
    int r = g * 64 + q * 16 + llo;
    boff[g] = ASUB + r * 64 + ((lhi ^ ((r >> 1) & 3)) << 4);
  }

  f4v acc[8][5];
#pragma unroll
  for (int fm = 0; fm < 8; ++fm)
#pragma unroll
    for (int g = 0; g < 5; ++g)
      acc[fm][g] = (f4v){0.f, 0.f, 0.f, 0.f};

  auto compute = [&](int buf) {
    const unsigned char* base = lds + buf * BUFSZ;
    s8v af[8], bv[5];
#pragma unroll
    for (int fm = 0; fm < 8; ++fm) af[fm] = *(const s8v*)(base + aoff[fm]);
#pragma unroll
    for (int g = 0; g < 5; ++g)  bv[g] = *(const s8v*)(base + boff[g]);
    __builtin_amdgcn_s_setprio(1);
#pragma unroll
    for (int fm = 0; fm < 8; ++fm)
#pragma unroll
      for (int g = 0; g < 5; ++g)
        acc[fm][g] = __builtin_amdgcn_mfma_f32_16x16x32_bf16(
            af[fm], bv[g], acc[fm][g], 0, 0, 0);
    __builtin_amdgcn_s_setprio(0);
  };

  // ---------- K loop: NT tiles, double-buffered, one barrier per step ----------
  do_stage(0, t0);
  __syncthreads();
  for (int t = 0; t < NT; ++t) {
    const int cur = t & 1;
    if (t + 1 < NT) do_stage(cur ^ 1, t0 + t + 1);
    compute(cur);
    __syncthreads();
  }

  const int hdl = q * 16 + llo;

  if constexpr (KS > 1) {
    // ---------- partial epilogue: store acc as bf16 z-partials ----------
#pragma unroll
    for (int fm = 0; fm < 8; ++fm) {
#pragma unroll
      for (int jj = 0; jj < 4; ++jj) {
        int m = bm * BM + mh * 128 + fm * 16 + lhi * 4 + jj;
        size_t base = (((size_t)(ks * M + m) * 8 + ht) * 5) * 64;
#pragma unroll
        for (int g = 0; g < 5; ++g)
          p.part[base + g * 64 + hdl] = f2bf(acc[fm][g][jj]);
      }
    }
  } else {
    // ---------- full epilogue: thread-local gate math ----------
    const int hd = ht * 64 + hdl;
    float bb[5];
#pragma unroll
    for (int g = 0; g < 5; ++g) bb[g] = p.bias[g][hd];

#pragma unroll
    for (int fm = 0; fm < 8; ++fm) {
#pragma unroll
      for (int jj = 0; jj < 4; ++jj) {
        int m = bm * BM + mh * 128 + fm * 16 + lhi * 4 + jj;
        if (m < M) {
          int b = m >> LOGNK, j = m & (NK - 1);
          float zi  = acc[fm][0][jj] + bb[0];
          float zfl = acc[fm][1][jj] + bb[1];
          float zfr = acc[fm][2][jj] + bb[2];
          float zo  = acc[fm][3][jj] + bb[3];
          float zc  = acc[fm][4][jj] + bb[4];
          float cl = 0.5f, cr = 0.5f;
          if constexpr (LEVEL > 1) {
            const unsigned short* cb =
                p.hcprev + ((size_t)b * NKP + 2 * j) * (2 * NH) + NH;
            cl = bf2f(cb[hd]);
            cr = bf2f(cb[2 * NH + hd]);
          }
          float cnew = sigf(zi) * tanhf(zc) + sigf(zfl) * cl + sigf(zfr) * cr;
          float hnew = sigf(zo) * tanhf(cnew);
          unsigned short* orow = p.hcout + ((size_t)b * NK + j) * (2 * NH);
          orow[hd] = f2bf(hnew);
          orow[NH + hd] = f2bf(cnew);
          int colout = (((j + 1) << LEVEL) - 2 - __popc(j)) + 1;
          p.out[((size_t)b * NMAX + colout) * NH + hd] = hnew;
          if (LEVEL == 1 && j == 0) p.out[(size_t)b * NMAX * NH + hd] = hnew;
          if constexpr (LEVEL == 8) { p.fh[b * NH + hd] = hnew; p.fc[b * NH + hd] = cnew; }
        }
      }
    }
  }
}

// Split-K combine: sum KS bf16 z-partials in fixed order (deterministic),
// apply gates, write all outputs.  One thread per (m, hd).
template<int LEVEL, int KS>
__global__ __launch_bounds__(256)
void lstm_combine(Params p) {
  constexpr int NK = NL >> LEVEL;
  constexpr int LOGNK = 8 - LEVEL;
  constexpr int NKP = NL >> (LEVEL - 1);
  constexpr int M = NB * NK;
  int t = blockIdx.x * 256 + threadIdx.x;       // t < M*512
  int m = t >> 9, hd = t & 511;
  int ht = hd >> 6, hdl = hd & 63;
  int b = m >> LOGNK, j = m & (NK - 1);

  float z[5];
#pragma unroll
  for (int g = 0; g < 5; ++g) z[g] = p.bias[g][hd];
  for (int ks = 0; ks < KS; ++ks) {
    size_t base = (((size_t)(ks * M + m) * 8 + ht) * 5) * 64;
#pragma unroll
    for (int g = 0; g < 5; ++g) z[g] += bf2f(p.part[base + g * 64 + hdl]);
  }
  const unsigned short* cb = p.hcprev + ((size_t)b * NKP + 2 * j) * (2 * NH) + NH;
  float cl = bf2f(cb[hd]);
  float cr = bf2f(cb[2 * NH + hd]);
  float cnew = sigf(z[0]) * tanhf(z[4]) + sigf(z[1]) * cl + sigf(z[2]) * cr;
  float hnew = sigf(z[3]) * tanhf(cnew);
  unsigned short* orow = p.hcout + ((size_t)b * NK + j) * (2 * NH);
  orow[hd] = f2bf(hnew);
  orow[NH + hd] = f2bf(cnew);
  int colout = (((j + 1) << LEVEL) - 2 - __popc(j)) + 1;
  p.out[((size_t)b * NMAX + colout) * NH + hd] = hnew;
  if constexpr (LEVEL == 8) { p.fh[b * NH + hd] = hnew; p.fc[b * NH + hd] = cnew; }
}

extern "C" void kernel_launch(void* const* d_in, const int* in_sizes, int n_in,
                              void* d_out, int out_size, void* d_ws, size_t ws_size,
                              hipStream_t stream) {
  unsigned short* wbf = (unsigned short*)d_ws;            // 2,621,440 elems (5.24 MB)
  unsigned short* R1  = wbf + (size_t)10 * NH * NH;       // 16,777,216 elems (33.55 MB)
  unsigned short* R2  = R1 + 16777216;                    // 16,777,216 elems (33.55 MB)
  // R1: embbf for level 1, then outputs of levels 2,4,6,8.
  // R2: outputs of levels 1,3,5,7.  Total ws use: 72.35 MB.
  // Split-K partials live in the IN buffer's tail (in-use prefix at level k
  // is <= 8.39 MB for k=4, <= 4.19 MB for k>=5): offset 6M elems (12 MB) for
  // level 4 (needs 10.49M elems, 6M+10.49M = 16.77M = exact fit), 4M elems
  // (8 MB) for levels 5-8 (max need 10.49M at level 5: 4M+10.49M <= 16.77M).

  PrepParams pp;
  for (int i = 0; i < 10; ++i) pp.u[i] = (const float*)d_in[2 + i];
  pp.emb  = (const float*)d_in[1];
  pp.wdst = wbf;
  pp.edst = R1;

  Params p;
  p.widx = (const int*)d_in[0];
  for (int g = 0; g < 5; ++g) p.bias[g] = (const float*)d_in[12 + g];
  p.wbf   = wbf;
  p.embbf = R1;
  p.part  = nullptr;
  p.out   = (float*)d_out;
  p.fh    = p.out + (size_t)NB * NMAX * NH;
  p.fc    = p.fh + NB * NH;

  prep_cvt<<<dim3(9280), dim3(256), 0, stream>>>(pp);

  unsigned short* lvlout[9];
  for (int k = 1; k <= 8; ++k) lvlout[k] = (k & 1) ? R2 : R1;

  p.hcprev = nullptr;     p.hcout = lvlout[1];
  lstm_level<1, 256, 1><<<dim3(64, 8), dim3(512), 0, stream>>>(p);
  p.hcprev = lvlout[1];   p.hcout = lvlout[2];
  lstm_level<2, 128, 1><<<dim3(64, 8), dim3(256), 0, stream>>>(p);
  p.hcprev = lvlout[2];   p.hcout = lvlout[3];
  lstm_level<3, 128, 1><<<dim3(32, 8), dim3(256), 0, stream>>>(p);

  // level 4: KS=2 (M=2048)
  p.hcprev = lvlout[3];   p.hcout = lvlout[4];
  p.part   = lvlout[3] + 6 * 1024 * 1024;
  lstm_level<4, 128, 2><<<dim3(16, 8, 2), dim3(256), 0, stream>>>(p);
  lstm_combine<4, 2><<<dim3(4096), dim3(256), 0, stream>>>(p);

  // level 5: KS=4 (M=1024)
  p.hcprev = lvlout[4];   p.hcout = lvlout[5];
  p.part   = lvlout[4] + 4 * 1024 * 1024;
  lstm_level<5, 128, 4><<<dim3(8, 8, 4), dim3(256), 0, stream>>>(p);
  lstm_combine<5, 4><<<dim3(2048), dim3(256), 0, stream>>>(p);

  // level 6: KS=4 (M=512)
  p.hcprev = lvlout[5];   p.hcout = lvlout[6];
  p.part   = lvlout[5] + 4 * 1024 * 1024;
  lstm_level<6, 128, 4><<<dim3(4, 8, 4), dim3(256), 0, stream>>>(p);
  lstm_combine<6, 4><<<dim3(1024), dim3(256), 0, stream>>>(p);

  // level 7: KS=8 (M=256)
  p.hcprev = lvlout[6];   p.hcout = lvlout[7];
  p.part   = lvlout[6] + 4 * 1024 * 1024;
  lstm_level<7, 128, 8><<<dim3(2, 8, 8), dim3(256), 0, stream>>>(p);
  lstm_combine<7, 8><<<dim3(512), dim3(256), 0, stream>>>(p);

  // level 8: KS=8 (M=128)
  p.hcprev = lvlout[7];   p.hcout = lvlout[8];
  p.part   = lvlout[7] + 4 * 1024 * 1024;
  lstm_level<8, 128, 8><<<dim3(1, 8, 8), dim3(256), 0, stream>>>(p);
  lstm_combine<8, 8><<<dim3(256), dim3(256), 0, stream>>>(p);
}